// Round 7
// baseline (1165.781 us; speedup 1.0000x reference)
//
#include <hip/hip_runtime.h>
#include <hip/hip_bf16.h>
#include <math.h>

#define H_ 100
#define W_ 152
#define HW_ 15200
#define C_ 512
#define A_ 9
#define NA_ 136800        // HW*A
#define PRE_NMS_ 6000
#define NB_PAD_ 6016      // PRE_NMS padded to 64
#define NWORDS_ 94        // ceil(6000/64)
#define POST_NMS_ 300
#define NSEL_ 8192        // compacted top-set padded to pow2

#define QH_ 102           // padded rows
#define QW_ 154           // padded cols
#define NQ_ (QH_ * QW_)   // 15708 padded positions

typedef __attribute__((ext_vector_type(8))) short short8;   // 8 bf16 (4 VGPRs)
typedef __attribute__((ext_vector_type(4))) float f32x4;    // MFMA C/D
typedef unsigned long long u64;

#define GLOAD_LDS16(g, l) \
    __builtin_amdgcn_global_load_lds( \
        (const __attribute__((address_space(1))) void*)(g), \
        (__attribute__((address_space(3))) void*)(l), 16, 0, 0)

// ---------------------------------------------------------------------------
// pack_x: fm (fp32 CHW) -> padded HWC bf16 3-term split arrays xp{h,m,l}.
// ---------------------------------------------------------------------------
__global__ __launch_bounds__(256) void pack_x(const float* __restrict__ fm,
                                              __hip_bfloat16* __restrict__ xph,
                                              __hip_bfloat16* __restrict__ xpm,
                                              __hip_bfloat16* __restrict__ xpl)
{
    __shared__ float t[64][65];
    const int tid = threadIdx.x;
    const int q0 = blockIdx.x * 64;
    const int c0 = blockIdx.y * 64;

    {
        const int qi = tid & 63;
        const int cs = tid >> 6;          // 0..3
        const int q = q0 + qi;
        int hp = q / QW_, wp = q - hp * QW_;
        bool inter = (q < NQ_) && (hp >= 1) && (hp <= 100) && (wp >= 1) && (wp <= 152);
        int p = inter ? ((hp - 1) * W_ + (wp - 1)) : 0;
#pragma unroll
        for (int cc = cs; cc < 64; cc += 4) {
            float v = inter ? fm[(size_t)(c0 + cc) * HW_ + p] : 0.f;
            t[cc][qi] = v;
        }
    }
    __syncthreads();
    {
        const int cl = tid & 63;
        const int qs = tid >> 6;
#pragma unroll
        for (int qq = qs; qq < 64; qq += 4) {
            int qg = q0 + qq;
            if (qg < NQ_) {
                float v = t[cl][qq];
                __hip_bfloat16 h = __float2bfloat16(v);
                float r1 = v - __bfloat162float(h);
                __hip_bfloat16 m = __float2bfloat16(r1);
                float r2 = r1 - __bfloat162float(m);
                __hip_bfloat16 l = __float2bfloat16(r2);
                size_t o = (size_t)qg * 512 + c0 + cl;
                xph[o] = h;
                xpm[o] = m;
                xpl[o] = l;
            }
        }
    }
}

// ---------------------------------------------------------------------------
// pack_w: cw[co][ci][3][3] fp32 -> MFMA B-fragment-ordered bf16 3-term split.
// ---------------------------------------------------------------------------
__global__ __launch_bounds__(256) void pack_w(const float* __restrict__ cw,
                                              __hip_bfloat16* __restrict__ bph,
                                              __hip_bfloat16* __restrict__ bpm,
                                              __hip_bfloat16* __restrict__ bpl)
{
    int id = blockIdx.x * 256 + threadIdx.x;      // 294912 total
    int lane = id & 63;
    int rest = id >> 6;
    int n16 = rest & 31;
    int tk = rest >> 5;
    int k32 = tk & 15;
    int t9 = tk >> 4;
    if (t9 >= 9) return;
    int ky = t9 / 3, kx = t9 - ky * 3;
    int n = n16 * 16 + (lane & 15);
    int kb = k32 * 32 + (lane >> 4) * 8;

    union H8 { short8 s; __hip_bfloat16 b[8]; } hv, mv, lv;
#pragma unroll
    for (int j = 0; j < 8; j++) {
        int ci = kb + j;
        float v = cw[(((size_t)n * 512 + ci) * 3 + ky) * 3 + kx];
        __hip_bfloat16 h = __float2bfloat16(v);
        float r1 = v - __bfloat162float(h);
        __hip_bfloat16 m = __float2bfloat16(r1);
        float r2 = r1 - __bfloat162float(m);
        hv.b[j] = h;
        mv.b[j] = m;
        lv.b[j] = __float2bfloat16(r2);
    }
    *(short8*)((short*)bph + (size_t)id * 8) = hv.s;
    *(short8*)((short*)bpm + (size_t)id * 8) = mv.s;
    *(short8*)((short*)bpl + (size_t)id * 8) = lv.s;
}

// ---------------------------------------------------------------------------
// conv_mfma: 3x3 conv as 9-tap implicit GEMM, bf16 3-term split, fp32 acc.
// global_load_lds width=16 staging (v3 structure, unchanged from R6 win).
// ---------------------------------------------------------------------------
__global__ __launch_bounds__(256, 2) void conv_mfma(
    const __hip_bfloat16* __restrict__ xph, const __hip_bfloat16* __restrict__ xpm,
    const __hip_bfloat16* __restrict__ xpl,
    const __hip_bfloat16* __restrict__ bph, const __hip_bfloat16* __restrict__ bpm,
    const __hip_bfloat16* __restrict__ bpl,
    const float* __restrict__ cb, float* __restrict__ xt)
{
    __shared__ short a_lds[24][64][8];   // 24 KB, slot = mf*3 + arr
    __shared__ short b_lds[24][64][8];   // 24 KB, slot = nf*3 + arr

    const int tid = threadIdx.x;
    const int wave = tid >> 6, lane = tid & 63;
    const int wm = wave >> 1, wn = wave & 1;
    const int mb = blockIdx.x, nb = blockIdx.y;

    const __hip_bfloat16* xarr[3] = {xph, xpm, xpl};
    const __hip_bfloat16* barr[3] = {bph, bpm, bpl};

    const int sBase = wave * 6;
    const short* aSrc[6];
    const short* bSrc[6];
#pragma unroll
    for (int i = 0; i < 6; i++) {
        int s = sBase + i;                // 0..23
        int f = s / 3, arr = s - 3 * (s / 3);
        int m = mb * 128 + f * 16 + (lane & 15);
        int hh = m / W_, ww = m - hh * W_;
        int q = (hh + 1) * QW_ + (ww + 1);
        aSrc[i] = (const short*)xarr[arr] + (size_t)q * 512 + (lane >> 4) * 8;
        bSrc[i] = (const short*)barr[arr] + (size_t)(nb * 8 + f) * 512 + lane * 8;
    }

    f32x4 acc[4][4];
#pragma unroll
    for (int f = 0; f < 4; f++)
#pragma unroll
        for (int g = 0; g < 4; g++)
            acc[f][g] = (f32x4){0.f, 0.f, 0.f, 0.f};

    for (int it = 0; it < 144; it++) {
        const int t9 = it >> 4;           // 144 = 9*16
        const int k32 = it & 15;
        const int t3 = t9 / 3;
        const int dy = t3 - 1, dx = t9 - t3 * 3 - 1;
        const int offA = ((dy * QW_ + dx) << 9) + (k32 << 5);  // shorts
        const int offB = it << 14;                              // shorts

        __syncthreads();
#pragma unroll
        for (int i = 0; i < 6; i++) {
            GLOAD_LDS16(aSrc[i] + offA, &a_lds[sBase + i][0][0]);
            GLOAD_LDS16(bSrc[i] + offB, &b_lds[sBase + i][0][0]);
        }
        __syncthreads();

        short8 ah[4], am[4], al[4];
#pragma unroll
        for (int f = 0; f < 4; f++) {
            ah[f] = *(const short8*)&a_lds[(wm * 4 + f) * 3 + 0][lane][0];
            am[f] = *(const short8*)&a_lds[(wm * 4 + f) * 3 + 1][lane][0];
            al[f] = *(const short8*)&a_lds[(wm * 4 + f) * 3 + 2][lane][0];
        }
#pragma unroll
        for (int g = 0; g < 4; g++) {
            short8 bh = *(const short8*)&b_lds[(wn * 4 + g) * 3 + 0][lane][0];
            short8 bm = *(const short8*)&b_lds[(wn * 4 + g) * 3 + 1][lane][0];
            short8 bl = *(const short8*)&b_lds[(wn * 4 + g) * 3 + 2][lane][0];
#pragma unroll
            for (int f = 0; f < 4; f++) {
                f32x4 a = acc[f][g];
                a = __builtin_amdgcn_mfma_f32_16x16x32_bf16(ah[f], bh, a, 0, 0, 0);
                a = __builtin_amdgcn_mfma_f32_16x16x32_bf16(ah[f], bm, a, 0, 0, 0);
                a = __builtin_amdgcn_mfma_f32_16x16x32_bf16(am[f], bh, a, 0, 0, 0);
                a = __builtin_amdgcn_mfma_f32_16x16x32_bf16(ah[f], bl, a, 0, 0, 0);
                a = __builtin_amdgcn_mfma_f32_16x16x32_bf16(al[f], bh, a, 0, 0, 0);
                a = __builtin_amdgcn_mfma_f32_16x16x32_bf16(am[f], bm, a, 0, 0, 0);
                acc[f][g] = a;
            }
        }
    }

    const int col = lane & 15, quad = lane >> 4;
#pragma unroll
    for (int g = 0; g < 4; g++) {
        int n = nb * 128 + (wn * 4 + g) * 16 + col;
        float bias = cb[n];
#pragma unroll
        for (int f = 0; f < 4; f++) {
            int m0 = mb * 128 + (wm * 4 + f) * 16 + quad * 4;
#pragma unroll
            for (int r = 0; r < 4; r++) {
                int m = m0 + r;
                if (m < HW_)
                    xt[(size_t)m * 512 + n] = fmaxf(acc[f][g][r] + bias, 0.f);
            }
        }
    }
}

// ---------------------------------------------------------------------------
// rpn_head v2: c = tid>>2 (16 distinct weight cache lines per wave-load
// instead of 54), float4 weight + LDS reads. FMA chain per output is
// bit-identical to v1 (ci ascending) -> no numerics change.
// ---------------------------------------------------------------------------
__device__ const float g_bx1[9] = {-84.f,-176.f,-360.f,-56.f,-120.f,-248.f,-36.f,-80.f,-168.f};
__device__ const float g_by1[9] = {-40.f,-88.f,-184.f,-56.f,-120.f,-248.f,-80.f,-168.f,-344.f};
__device__ const float g_bx2[9] = {99.f,191.f,375.f,71.f,135.f,263.f,51.f,95.f,183.f};
__device__ const float g_by2[9] = {55.f,103.f,199.f,71.f,135.f,263.f,95.f,183.f,359.f};

__global__ __launch_bounds__(256) void rpn_head(
    const float* __restrict__ xt,
    const float* __restrict__ cls_w, const float* __restrict__ cls_b,
    const float* __restrict__ bbox_w, const float* __restrict__ bbox_b,
    const float* __restrict__ im_info,
    float* __restrict__ scores, float4* __restrict__ boxes)
{
    __shared__ float xl[16 * 512];
    __shared__ float raw[16][56];
    const int tid = threadIdx.x;
    const int p0 = blockIdx.x * 16;

    {
        const float4* src = (const float4*)(xt + (size_t)p0 * 512);
        float4* dst = (float4*)xl;
        for (int i = tid; i < 2048; i += 256) dst[i] = src[i];
    }
    __syncthreads();

    if (tid < 216) {
        int c  = tid >> 2;               // 0..53
        int pg = tid & 3;                // positions pg*4 .. pg*4+3
        const float* wrow = (c < 18) ? (cls_w + (size_t)c * 512)
                                     : (bbox_w + (size_t)(c - 18) * 512);
        float b = (c < 18) ? cls_b[c] : bbox_b[c - 18];
        const float4* w4 = (const float4*)wrow;
        const float4* x0 = (const float4*)(xl + (size_t)(pg * 4) * 512);
        float a0 = b, a1 = b, a2 = b, a3 = b;
        for (int q = 0; q < 128; q++) {
            float4 wv = w4[q];
            float4 xa = x0[q];
            float4 xb = x0[128 + q];
            float4 xc = x0[256 + q];
            float4 xd = x0[384 + q];
            a0 = fmaf(wv.x, xa.x, a0); a0 = fmaf(wv.y, xa.y, a0);
            a0 = fmaf(wv.z, xa.z, a0); a0 = fmaf(wv.w, xa.w, a0);
            a1 = fmaf(wv.x, xb.x, a1); a1 = fmaf(wv.y, xb.y, a1);
            a1 = fmaf(wv.z, xb.z, a1); a1 = fmaf(wv.w, xb.w, a1);
            a2 = fmaf(wv.x, xc.x, a2); a2 = fmaf(wv.y, xc.y, a2);
            a2 = fmaf(wv.z, xc.z, a2); a2 = fmaf(wv.w, xc.w, a2);
            a3 = fmaf(wv.x, xd.x, a3); a3 = fmaf(wv.y, xd.y, a3);
            a3 = fmaf(wv.z, xd.z, a3); a3 = fmaf(wv.w, xd.w, a3);
        }
        raw[pg * 4 + 0][c] = a0;
        raw[pg * 4 + 1][c] = a1;
        raw[pg * 4 + 2][c] = a2;
        raw[pg * 4 + 3][c] = a3;
    }
    __syncthreads();

    if (tid < 144) {
        int pos = tid / 9;
        int a   = tid % 9;
        int p = p0 + pos;
        int hh = p / 152;
        int ww = p - hh * 152;

        float s0 = raw[pos][a], s1 = raw[pos][9 + a];
        float fg = 1.f / (1.f + expf(s0 - s1));

        float dx = raw[pos][18 + 4 * a + 0];
        float dy = raw[pos][18 + 4 * a + 1];
        float dw = raw[pos][18 + 4 * a + 2];
        float dh = raw[pos][18 + 4 * a + 3];

        float sx = ww * 16.f, sy = hh * 16.f;
        float ax1 = g_bx1[a] + sx, ay1 = g_by1[a] + sy;
        float ax2 = g_bx2[a] + sx, ay2 = g_by2[a] + sy;
        float aw = ax2 - ax1 + 1.f, ah = ay2 - ay1 + 1.f;
        float axc = ax1 + 0.5f * aw, ayc = ay1 + 0.5f * ah;

        float px = dx * aw + axc, py = dy * ah + ayc;
        float pw = expf(dw) * aw, ph = expf(dh) * ah;
        float x1 = px - 0.5f * pw, y1 = py - 0.5f * ph;
        float x2 = px + 0.5f * pw, y2 = py + 0.5f * ph;

        float imh = im_info[0], imw = im_info[1], scl = im_info[2];
        x1 = fminf(fmaxf(x1, 0.f), imw - 1.f);
        y1 = fminf(fmaxf(y1, 0.f), imh - 1.f);
        x2 = fminf(fmaxf(x2, 0.f), imw - 1.f);
        y2 = fminf(fmaxf(y2, 0.f), imh - 1.f);

        float wd = x2 - x1 + 1.f, hd = y2 - y1 + 1.f;
        bool valid = (wd >= 16.f * scl) && (hd >= 16.f * scl);

        int idx = p * 9 + a;
        scores[idx] = valid ? fg : -1000000000.f;
        boxes[idx] = make_float4(x1, y1, x2, y2);
    }
}

// ---------------------------------------------------------------------------
// Exact top-6000 via u64 radix select (4 x 16-bit passes, descending).
// key = sortable(score)<<32 | ~idx  -> all keys distinct, so the rank-6000
// key K* is unique and |{key >= K*}| == 6000 exactly. Tie-break == lax.top_k.
// ---------------------------------------------------------------------------
__device__ __forceinline__ u64 make_key(float sc, int i)
{
    unsigned u = __float_as_uint(sc);
    u = (u & 0x80000000u) ? ~u : (u | 0x80000000u);
    return ((u64)u << 32) | (unsigned)(0xFFFFFFFFu - (unsigned)i);
}

__global__ void zero_hist(unsigned* __restrict__ hist, u64* __restrict__ state)
{
    int i = blockIdx.x * 256 + threadIdx.x;
    if (i < 65536) hist[i] = 0u;
    if (i == 0) { state[0] = 0ull; state[1] = (u64)PRE_NMS_; }
}

__global__ __launch_bounds__(256) void radix_hist(const float* __restrict__ scores,
                                                  unsigned* __restrict__ hist,
                                                  const u64* __restrict__ state,
                                                  int pass)
{
    int i = blockIdx.x * 256 + threadIdx.x;
    if (i >= NA_) return;
    u64 key = make_key(scores[i], i);
    int sh = 48 - 16 * pass;
    if (pass > 0 && ((key ^ state[0]) >> (sh + 16)) != 0) return;
    atomicAdd(&hist[(unsigned)((key >> sh) & 0xFFFF)], 1u);
}

__global__ __launch_bounds__(1024) void radix_scan(unsigned* __restrict__ hist,
                                                   u64* __restrict__ state,
                                                   unsigned* __restrict__ cnt,
                                                   u64* __restrict__ buf,
                                                   int pass)
{
    __shared__ unsigned s[1024];
    const int t = threadIdx.x;
    unsigned local = 0;
#pragma unroll 8
    for (int i = 0; i < 64; i++) local += hist[t * 64 + i];
    s[t] = local;
    __syncthreads();
    for (int off = 1; off < 1024; off <<= 1) {
        unsigned v = (t + off < 1024) ? s[t + off] : 0u;
        __syncthreads();
        s[t] += v;
        __syncthreads();
    }
    unsigned rank = (unsigned)state[1];
    unsigned Sincl = s[t];
    unsigned Snext = (t < 1023) ? s[t + 1] : 0u;
    if (Sincl >= rank && Snext < rank) {
        unsigned cum = Snext;
        for (int d = t * 64 + 63; d >= t * 64; d--) {
            unsigned h = hist[d];
            if (cum + h >= rank) {
                state[0] |= ((u64)(unsigned)d) << (48 - 16 * pass);
                state[1] = (u64)(rank - cum);
                break;
            }
            cum += h;
        }
    }
    // zero own bins for next pass (each thread touches only its own chunk)
#pragma unroll 8
    for (int i = 0; i < 64; i++) hist[t * 64 + i] = 0u;
    if (pass == 3) {
        if (t == 0) *cnt = 0u;
#pragma unroll
        for (int i = 0; i < NSEL_ / 1024; i++) buf[t * (NSEL_ / 1024) + i] = 0ull;
    }
}

__global__ __launch_bounds__(256) void radix_compact(const float* __restrict__ scores,
                                                     const u64* __restrict__ state,
                                                     unsigned* __restrict__ cnt,
                                                     u64* __restrict__ buf)
{
    int i = blockIdx.x * 256 + threadIdx.x;
    if (i >= NA_) return;
    u64 key = make_key(scores[i], i);
    if (key >= state[0]) {
        unsigned p = atomicAdd(cnt, 1u);
        if (p < NSEL_) buf[p] = key;
    }
}

// ---------------------------------------------------------------------------
// Bitonic sort of the 8192 compacted keys (descending; zeros sink).
// ---------------------------------------------------------------------------
__device__ __forceinline__ void cex(u64* s, int i, int l, bool desc)
{
    u64 a = s[i], b = s[l];
    if (desc ? (a < b) : (a > b)) { s[i] = b; s[l] = a; }
}

__global__ __launch_bounds__(256) void sel_local_sort(u64* __restrict__ buf)
{
    __shared__ u64 s[4096];
    const int tid = threadIdx.x;
    const int base = blockIdx.x * 4096;
    for (int i = tid; i < 4096; i += 256) s[i] = buf[base + i];
    __syncthreads();
    for (int k = 2; k <= 4096; k <<= 1) {
        for (int j = k >> 1; j > 0; j >>= 1) {
#pragma unroll
            for (int m = 0; m < 8; m++) {
                int p = tid + m * 256;
                int i = ((p & ~(j - 1)) << 1) | (p & (j - 1));
                bool desc = (((base + i) & k) == 0);
                cex(s, i, i | j, desc);
            }
            __syncthreads();
        }
    }
    for (int i = tid; i < 4096; i += 256) buf[base + i] = s[i];
}

__global__ void sel_global(u64* __restrict__ buf, int j, int k)
{
    int p = blockIdx.x * 256 + threadIdx.x;
    int i = ((p & ~(j - 1)) << 1) | (p & (j - 1));
    int l = i | j;
    bool desc = ((i & k) == 0);
    u64 a = buf[i], b = buf[l];
    if (desc ? (a < b) : (a > b)) { buf[i] = b; buf[l] = a; }
}

__global__ __launch_bounds__(256) void sel_local_merge(u64* __restrict__ buf, int k)
{
    __shared__ u64 s[4096];
    const int tid = threadIdx.x;
    const int base = blockIdx.x * 4096;
    const bool desc = ((base & k) == 0);
    for (int i = tid; i < 4096; i += 256) s[i] = buf[base + i];
    __syncthreads();
    for (int j = 2048; j > 0; j >>= 1) {
#pragma unroll
        for (int m = 0; m < 8; m++) {
            int p = tid + m * 256;
            int i = ((p & ~(j - 1)) << 1) | (p & (j - 1));
            cex(s, i, i | j, desc);
        }
        __syncthreads();
    }
    for (int i = tid; i < 4096; i += 256) buf[base + i] = s[i];
}

// ---------------------------------------------------------------------------
// Gather top-6000 (padded to 6016) boxes/scores/areas in sorted order
// ---------------------------------------------------------------------------
__global__ void gather_top(const u64* __restrict__ keys,
                           const float* __restrict__ scores,
                           const float4* __restrict__ boxes,
                           float4* __restrict__ nb, float* __restrict__ sc,
                           float* __restrict__ area)
{
    int r = blockIdx.x * 256 + threadIdx.x;
    if (r >= NB_PAD_) return;
    if (r < PRE_NMS_) {
        u64 key = keys[r];
        unsigned idx = 0xFFFFFFFFu - (unsigned)(key & 0xFFFFFFFFull);
        float4 b = boxes[idx];
        nb[r] = b;
        sc[r] = scores[idx];
        area[r] = (b.z - b.x + 1.f) * (b.w - b.y + 1.f);
    } else {
        nb[r] = make_float4(0.f, 0.f, 0.f, 0.f);
        sc[r] = -1000000000.f;
        area[r] = 1.f;
    }
}

// ---------------------------------------------------------------------------
// NMS suppression bitmatrix + diagonal words
// ---------------------------------------------------------------------------
__global__ __launch_bounds__(64) void nms_mask(const float4* __restrict__ nb,
                                               const float* __restrict__ area,
                                               u64* __restrict__ mask,
                                               u64* __restrict__ diag)
{
    __shared__ float4 cbox[64];
    __shared__ float carea[64];
    const int t = threadIdx.x;
    const int cbk = blockIdx.x, rb = blockIdx.y;
    const int jBase = cbk * 64;
    cbox[t] = nb[jBase + t];
    carea[t] = area[jBase + t];
    __syncthreads();

    const int i = rb * 64 + t;
    const float4 bi = nb[i];
    const float ai = area[i];
    u64 bits = 0ull;
#pragma unroll 8
    for (int b = 0; b < 64; b++) {
        int j = jBase + b;
        if (j > i) {
            float4 bj = cbox[b];
            float xx1 = fmaxf(bi.x, bj.x), yy1 = fmaxf(bi.y, bj.y);
            float xx2 = fminf(bi.z, bj.z), yy2 = fminf(bi.w, bj.w);
            float iw = fmaxf(0.f, xx2 - xx1 + 1.f);
            float ih = fmaxf(0.f, yy2 - yy1 + 1.f);
            float inter = iw * ih;
            float iou = inter / (ai + carea[b] - inter);
            if (iou > 0.7f) bits |= (1ull << b);
        }
    }
    mask[(size_t)i * NWORDS_ + cbk] = bits;
    if (cbk == rb) diag[i] = bits;
}

// ---------------------------------------------------------------------------
// Block-serial NMS scan (4 waves, speculative row loads, LDS remv)
// ---------------------------------------------------------------------------
__device__ __forceinline__ u64 readlane_u64(u64 v, int l)
{
    unsigned int lo = (unsigned int)__builtin_amdgcn_readlane((int)(unsigned int)(v & 0xffffffffull), l);
    unsigned int hi = (unsigned int)__builtin_amdgcn_readlane((int)(unsigned int)(v >> 32), l);
    return ((u64)hi << 32) | (u64)lo;
}

__global__ __launch_bounds__(256) void nms_scan(const u64* __restrict__ mask,
                                                const u64* __restrict__ diag,
                                                int* __restrict__ keep)
{
    __shared__ u64 dlds[NB_PAD_];
    __shared__ unsigned rlo[NWORDS_], rhi[NWORDS_];
    __shared__ u64 aliveSh;
    const int tid = threadIdx.x;
    const int wave = tid >> 6, lane = tid & 63;

    for (int i = tid; i < NB_PAD_; i += 256) dlds[i] = diag[i];
    if (tid < NWORDS_) { rlo[tid] = 0u; rhi[tid] = 0u; }
    __syncthreads();

    for (int c = 0; c < NWORDS_; c++) {
        u64 ext = ((u64)rhi[c] << 32) | (u64)rlo[c];
        u64 aliveP = ~ext;

        u64 mysel = aliveP & (0xFFFFull << (wave * 16));
        int rb[16];
        int n = 0;
        while (mysel) { rb[n++] = (int)__builtin_ctzll(mysel); mysel &= mysel - 1; }

        u64 v0[16], v1[16];
#pragma unroll
        for (int i = 0; i < 16; i++) {
            if (i < n) {
                const u64* row = mask + (size_t)(c * 64 + rb[i]) * NWORDS_;
                v0[i] = row[lane];
                v1[i] = (lane < NWORDS_ - 64) ? row[64 + lane] : 0ull;
            }
        }

        if (wave == 0) {
            u64 myD = dlds[c * 64 + lane];
            u64 alive = aliveP, todo = aliveP;
            while (todo) {
                int l = (int)__builtin_ctzll(todo);
                todo &= todo - 1;
                u64 d = readlane_u64(myD, l);
                alive &= ~d;
                todo &= ~d;
            }
            keep[c * 64 + lane] = (int)((alive >> lane) & 1ull);
            if (lane == 0) aliveSh = alive;
        }
        __syncthreads();

        u64 alive = aliveSh;
        u64 d0 = 0ull, d1 = 0ull;
#pragma unroll
        for (int i = 0; i < 16; i++) {
            if (i < n && ((alive >> rb[i]) & 1ull)) { d0 |= v0[i]; d1 |= v1[i]; }
        }
        if (d0) {
            atomicOr(&rlo[lane], (unsigned)d0);
            atomicOr(&rhi[lane], (unsigned)(d0 >> 32));
        }
        if (lane < NWORDS_ - 64 && d1) {
            atomicOr(&rlo[64 + lane], (unsigned)d1);
            atomicOr(&rhi[64 + lane], (unsigned)(d1 >> 32));
        }
        __syncthreads();
    }
}

// ---------------------------------------------------------------------------
// Final: top-300 of kept (then non-kept in index order to fill) -> rois
// ---------------------------------------------------------------------------
__global__ __launch_bounds__(64) void final_out(const int* __restrict__ keep,
                                                const float* __restrict__ sc,
                                                const float4* __restrict__ nb,
                                                float* __restrict__ out)
{
    __shared__ int sel[POST_NMS_];
    const int lane = threadIdx.x;
    const u64 lmask = (lane == 0) ? 0ull : ((~0ull) >> (64 - lane));

    int cnt = 0;
    for (int c = 0; c < NWORDS_ && cnt < POST_NMS_; c++) {
        int j = c * 64 + lane;
        bool k = (j < PRE_NMS_) && keep[j] && (sc[j] > -5e8f);
        u64 bal = __ballot(k);
        int pos = cnt + __popcll(bal & lmask);
        if (k && pos < POST_NMS_) sel[pos] = j;
        cnt += __popcll(bal);
    }
    if (cnt < POST_NMS_) {
        for (int c = 0; c < NWORDS_ && cnt < POST_NMS_; c++) {
            int j = c * 64 + lane;
            bool k = (j < PRE_NMS_) && !(keep[j] && (sc[j] > -5e8f));
            u64 bal = __ballot(k);
            int pos = cnt + __popcll(bal & lmask);
            if (k && pos < POST_NMS_) sel[pos] = j;
            cnt += __popcll(bal);
        }
    }
    __syncthreads();
    for (int i = lane; i < POST_NMS_; i += 64) {
        int j = sel[i];
        float4 b = nb[j];
        out[i * 5 + 0] = 0.f;
        out[i * 5 + 1] = b.x;
        out[i * 5 + 2] = b.y;
        out[i * 5 + 3] = b.z;
        out[i * 5 + 4] = b.w;
    }
}

// ---------------------------------------------------------------------------
extern "C" void kernel_launch(void* const* d_in, const int* in_sizes, int n_in,
                              void* d_out, int out_size, void* d_ws, size_t ws_size,
                              hipStream_t stream)
{
    const float* fm      = (const float*)d_in[0];
    const float* im_info = (const float*)d_in[1];
    const float* conv_w  = (const float*)d_in[2];
    const float* conv_b  = (const float*)d_in[3];
    const float* cls_w   = (const float*)d_in[4];
    const float* cls_b   = (const float*)d_in[5];
    const float* bbox_w  = (const float*)d_in[6];
    const float* bbox_b  = (const float*)d_in[7];
    float* out = (float*)d_out;

    char* ws = (char*)d_ws;
    size_t off = 0;
    auto alloc = [&](size_t bytes) -> void* {
        void* p = ws + off;
        off = (off + bytes + 255) & ~(size_t)255;
        return p;
    };
    // persistent across phases
    float* xt = (float*)alloc((size_t)HW_ * 512 * 4);   // 31.1 MB

    // phase A (conv): bf16 split arrays. phase B (post-conv): rest. Aliased.
    size_t phase_base = off;
    __hip_bfloat16* xph = (__hip_bfloat16*)alloc((size_t)NQ_ * 512 * 2);
    __hip_bfloat16* xpm = (__hip_bfloat16*)alloc((size_t)NQ_ * 512 * 2);
    __hip_bfloat16* xpl = (__hip_bfloat16*)alloc((size_t)NQ_ * 512 * 2);
    __hip_bfloat16* bph = (__hip_bfloat16*)alloc((size_t)9 * 512 * 512 * 2);
    __hip_bfloat16* bpm = (__hip_bfloat16*)alloc((size_t)9 * 512 * 512 * 2);
    __hip_bfloat16* bpl = (__hip_bfloat16*)alloc((size_t)9 * 512 * 512 * 2);

    off = phase_base;  // alias: phase-B buffers reuse phase-A memory
    float* scores  = (float*)alloc((size_t)NA_ * 4);
    float4* boxes  = (float4*)alloc((size_t)NA_ * 16);
    unsigned* hist = (unsigned*)alloc((size_t)65536 * 4);
    u64* state     = (u64*)alloc(2 * 8);
    unsigned* cnt  = (unsigned*)alloc(4);
    u64* buf       = (u64*)alloc((size_t)NSEL_ * 8);
    float4* nb     = (float4*)alloc((size_t)NB_PAD_ * 16);
    float* sc      = (float*)alloc((size_t)NB_PAD_ * 4);
    float* area    = (float*)alloc((size_t)NB_PAD_ * 4);
    u64* mask      = (u64*)alloc((size_t)NB_PAD_ * NWORDS_ * 8);
    u64* diag      = (u64*)alloc((size_t)NB_PAD_ * 8);
    int* keep      = (int*)alloc((size_t)NB_PAD_ * 4);

    pack_x<<<dim3(246, 8), 256, 0, stream>>>(fm, xph, xpm, xpl);
    pack_w<<<dim3(1152), 256, 0, stream>>>(conv_w, bph, bpm, bpl);
    conv_mfma<<<dim3(119, 4), 256, 0, stream>>>(xph, xpm, xpl, bph, bpm, bpl,
                                                conv_b, xt);
    rpn_head<<<dim3(950), 256, 0, stream>>>(xt, cls_w, cls_b, bbox_w, bbox_b,
                                            im_info, scores, boxes);
    // exact top-6000: radix select + compact + 8K bitonic sort
    zero_hist<<<dim3(256), 256, 0, stream>>>(hist, state);
    for (int pass = 0; pass < 4; pass++) {
        radix_hist<<<dim3((NA_ + 255) / 256), 256, 0, stream>>>(scores, hist, state, pass);
        radix_scan<<<dim3(1), 1024, 0, stream>>>(hist, state, cnt, buf, pass);
    }
    radix_compact<<<dim3((NA_ + 255) / 256), 256, 0, stream>>>(scores, state, cnt, buf);
    sel_local_sort<<<dim3(2), 256, 0, stream>>>(buf);
    sel_global<<<dim3(NSEL_ / 2 / 256), 256, 0, stream>>>(buf, 4096, 8192);
    sel_local_merge<<<dim3(2), 256, 0, stream>>>(buf, 8192);

    gather_top<<<dim3((NB_PAD_ + 255) / 256), 256, 0, stream>>>(buf, scores, boxes,
                                                                nb, sc, area);
    nms_mask<<<dim3(NWORDS_, NWORDS_), 64, 0, stream>>>(nb, area, mask, diag);
    nms_scan<<<dim3(1), 256, 0, stream>>>(mask, diag, keep);
    final_out<<<dim3(1), 64, 0, stream>>>(keep, sc, nb, out);
}